// Round 6
// baseline (395.853 us; speedup 1.0000x reference)
//
#include <hip/hip_runtime.h>

// ---------- constants ----------
#define B_   16
#define C_   256
#define OC_  256
#define H_   64
#define W_   64

typedef __attribute__((ext_vector_type(8))) __bf16 bf16x8;
typedef __attribute__((ext_vector_type(4))) float  f32x4;

__device__ __forceinline__ short f2bf(float f) {
    unsigned u = __float_as_uint(f);
    u += 0x7fffu + ((u >> 16) & 1u);
    return (short)(u >> 16);
}
__device__ __forceinline__ unsigned pk2(float a, float b) {
    return (unsigned(f2bf(a)) & 0xffffu) | (unsigned(f2bf(b)) << 16);
}
__device__ __forceinline__ void gll16(const void* g, void* l) {
    __builtin_amdgcn_global_load_lds(
        (const __attribute__((address_space(1))) unsigned int*)g,
        (__attribute__((address_space(3))) unsigned int*)l,
        16, 0, 0);
}

// ---------- kernel 1: x (fp32, NCHW) -> x_t (bf16, [b][y][x][c]) + pooled atomics ----------
__global__ __launch_bounds__(256) void k_transpose_pool(
        const float* __restrict__ x, short* __restrict__ xt, float* __restrict__ pooled) {
    int y = blockIdx.x, b = blockIdx.y, t = threadIdx.x;
    int si = y >> 4;
    int lane = t & 63, wv = t >> 6;
    int xq = lane & 15, cw = lane >> 4;
    __shared__ float tile[64 * 67];   // stride 67: both phases ~2-way (free)

    for (int cc = 0; cc < 4; ++cc) {
        int cbase = cc * 64;
        if (cc) __syncthreads();
        #pragma unroll
        for (int r = 0; r < 4; ++r) {
            int c_l = r * 16 + wv * 4 + cw;
            float4 v = *(const float4*)&x[(((size_t)b * C_ + cbase + c_l) * H_ + y) * W_ + xq * 4];
            float* tp = &tile[c_l * 67 + xq * 4];
            tp[0] = v.x; tp[1] = v.y; tp[2] = v.z; tp[3] = v.w;
            float s = v.x + v.y + v.z + v.w;       // pooling partial (4 x)
            s += __shfl_xor(s, 1);
            s += __shfl_xor(s, 2);
            if ((lane & 3) == 0)
                atomicAdd(&pooled[((b * 4 + si) * 4 + (xq >> 2)) * 256 + cbase + c_l], s);
        }
        __syncthreads();
        #pragma unroll
        for (int r2 = 0; r2 < 2; ++r2) {
            int u = r2 * 256 + t;
            int xx = u >> 3, cgl = u & 7;
            float f[8];
            #pragma unroll
            for (int j = 0; j < 8; ++j) f[j] = tile[(cgl * 8 + j) * 67 + xx];
            uint4 pkv;
            pkv.x = pk2(f[0], f[1]); pkv.y = pk2(f[2], f[3]);
            pkv.z = pk2(f[4], f[5]); pkv.w = pk2(f[6], f[7]);
            *(uint4*)&xt[(((size_t)b * H_ + y) * W_ + xx) * C_ + cbase + cgl * 8] = pkv;
        }
    }
}

// ---------- kernel 2: routing head -> r[b][k][c] ----------
__global__ __launch_bounds__(256) void k_route(
        const float* __restrict__ pooled, const float* __restrict__ rconv_w,
        const float* __restrict__ rconv_b, const float* __restrict__ fc_w,
        const float* __restrict__ fc_b, float* __restrict__ r_buf) {
    int b = blockIdx.x >> 2;
    int slice = blockIdx.x & 3;
    int t = threadIdx.x;
    int lane = t & 63, wv = t >> 6;
    __shared__ float pl[16][257];
    __shared__ float y1[256];

    #pragma unroll
    for (int q = 0; q < 16; ++q)
        pl[q][t] = pooled[b * 4096 + q * 256 + t] * (1.0f / 256.0f);
    __syncthreads();
    {   // rconv + relu: redundant across the 4 slices (trivial cost)
        int rcc = t >> 4, ss = t & 15;
        float acc = rconv_b[rcc];
        #pragma unroll 8
        for (int c = 0; c < 256; ++c)
            acc += pl[ss][c] * rconv_w[rcc * 256 + c];
        y1[rcc * 16 + ss] = fmaxf(acc, 0.f);
    }
    __syncthreads();
    // fc: 192 outputs per block, 48 per wave
    #pragma unroll 4
    for (int i = 0; i < 48; ++i) {
        int e = slice * 192 + wv * 48 + i;
        const float* row = fc_w + (size_t)e * 256;
        float p = y1[lane]       * row[lane]
                + y1[lane + 64]  * row[lane + 64]
                + y1[lane + 128] * row[lane + 128]
                + y1[lane + 192] * row[lane + 192];
        #pragma unroll
        for (int d = 1; d < 64; d <<= 1)
            p += __shfl_xor(p, d);
        if (lane == 0) {
            float a = fmaxf(p + fc_b[e], 0.f);
            r_buf[(size_t)b * 768 + e] = 1.f / (1.f + __expf(-a));
        }
    }
}

// ---------- kernel 3: combine experts -> wcomb in MFMA-FRAGMENT order ----------
// Layout: [b][tap9][ccs8][og16] x 1KB-fragment [ol16][quad4][ch8] (shorts).
// k_conv wave reads one contiguous 1KB per fragment (lanes permuted inside
// the span -> fully coalesced). k_combine per-o writes are 64B segments
// (R5's [quad][ol][ch] order made them 16B -> write regression; fixed).
__global__ __launch_bounds__(256) void k_combine(
        const float* __restrict__ E, const float* __restrict__ r_buf,
        short* __restrict__ wcomb) {
    int o = blockIdx.x;        // 0..255
    int b0 = blockIdx.y * 4;   // 4 b's per block
    int t = threadIdx.x;
    __shared__ float eT[3][2304];
    #pragma unroll
    for (int k = 0; k < 3; ++k)
        #pragma unroll
        for (int q = 0; q < 9; ++q)
            eT[k][q * 256 + t] = E[((size_t)k * OC_ + o) * 2304 + q * 256 + t];
    __syncthreads();
    int c = t;
    int ccs = (c >> 5);                                        // cc*2+s (0..7)
    int sub = (o & 15) * 32 + ((c >> 3) & 3) * 8 + (c & 7);    // ol/quad/ch
    int og  = o >> 4;
    #pragma unroll
    for (int bb = 0; bb < 4; ++bb) {
        int b = b0 + bb;
        float r0 = r_buf[(size_t)b * 768 + c];
        float r1 = r_buf[(size_t)b * 768 + 256 + c];
        float r2 = r_buf[(size_t)b * 768 + 512 + c];
        short* wo = wcomb + (size_t)b * 589824;
        #pragma unroll
        for (int tap = 0; tap < 9; ++tap) {
            float v = r0 * eT[0][c * 9 + tap] + r1 * eT[1][c * 9 + tap]
                    + r2 * eT[2][c * 9 + tap];
            wo[((tap * 8 + ccs) * 16 + og) * 512 + sub] = f2bf(v);
        }
    }
}

// ---------- kernel 4: implicit-GEMM conv, 6 super-phases (tj row-sharing) ----------
// R5 post-mortem: pipes additive (MFMA 31 + LDS 23 + VALU 11.5 ~ 72us).
// Taps sharing tj read the SAME 4 win rows -> fold ti inside: per (s,tj)
// super-phase read bv[4 rows][4 xq] (16 ds_read_b128, was 24 for the same
// MFMAs) then run ti3 x mb4 x rr2 x xq4 = 96 MFMA. LDS reads/wave-cc
// 144 -> 96. A in registers, 2-deep ping-pong A[2][12] prefetched one
// super-phase ahead (coalesced 1KB fragment loads). No barriers inside cc.
__global__ __launch_bounds__(256, 2) void k_conv(
        const short* __restrict__ xt, const short* __restrict__ wcomb,
        float* __restrict__ out, const short* __restrict__ zbuf) {
    int lin  = blockIdx.x;
    int work = (lin & 7) * 64 + (lin >> 3);   // XCD-contiguous: 2 samples/XCD
    int b      = work >> 5;
    int o_base = ((work >> 4) & 1) * 128;
    int y0     = (work & 15) * 4;             // 4 output rows per block

    int t = threadIdx.x;
    int lane = t & 63, w = t >> 6;
    int quad = lane >> 4, l15 = lane & 15;

    __shared__ __align__(16) short win[6 * 64 * 64];   // rows y0-1..y0+4, 48 KB only

    int zoff = (int)(zbuf - xt);               // halo rows redirect into zbuf

    // window staging offsets (12 rounds x 256 threads = 3072 tasks)
    int woff[12];
    #pragma unroll
    for (int r = 0; r < 12; ++r) {
        int u = r * 256 + t;
        int pos = u >> 3, sp = u & 7;
        int wrow = pos >> 6, xc = pos & 63;
        int yy = y0 - 1 + wrow;
        int ss = sp ^ (xc & 7);                 // XOR swizzle at source
        woff[r] = ((unsigned)yy < 64u)
            ? ((b * 64 + yy) * 64 + xc) * 256 + ss * 8
            : zoff;
    }

    int m_base = (w & 1) * 64;
    int ry0    = (w >> 1) * 2;                 // output rows {0,1} or {2,3}

    // A fragment base (shorts): [b][tap][ccs][og][ol][quad][ch]
    // lane (quad,l15) -> offset l15*32 + quad*8 within each 1KB fragment.
    const short* pA = wcomb + (size_t)b * 589824
                    + ((o_base + m_base) >> 4) * 512 + l15 * 32 + quad * 8;

    f32x4 acc[4][8];
    #pragma unroll
    for (int i = 0; i < 4; ++i)
        #pragma unroll
        for (int j = 0; j < 8; ++j) acc[i][j] = {0.f, 0.f, 0.f, 0.f};

    bf16x8 A[2][12];   // [parity][ti*4+mb], fully static indexing

    for (int cc = 0; cc < 4; ++cc) {
        int ccOff = cc * 64;                   // xt channel offset (shorts)
        // stage window (direct-to-LDS; prev-cc tail barrier protects reuse)
        #pragma unroll
        for (int r = 0; r < 12; ++r)
            gll16(xt + woff[r] + ccOff, &win[(r * 256 + w * 64) * 8]);

        if (cc == 0) {   // preload super-phases 0 (tj0,s0) and 1 (tj0,s1)
            #pragma unroll
            for (int ti = 0; ti < 3; ++ti)
                #pragma unroll
                for (int mb = 0; mb < 4; ++mb) {
                    A[0][ti * 4 + mb] = *(const bf16x8*)(pA
                        + ((ti * 3) * 8 + 0) * 8192 + mb * 512);
                    A[1][ti * 4 + mb] = *(const bf16x8*)(pA
                        + ((ti * 3) * 8 + 1) * 8192 + mb * 512);
                }
        }
        __syncthreads();   // win ready (drains gll16; A preloads by reg dep)

        // 6 super-phases = (tj,s); all ti folded inside. No barriers.
        #pragma unroll
        for (int sp = 0; sp < 6; ++sp) {
            const int tj = sp >> 1, s = sp & 1;
            const int slog = s * 4 + quad;

            int xsA[4], lofs[4];
            bool okA[4];
            #pragma unroll
            for (int xq = 0; xq < 4; ++xq) {
                int xc = xq * 16 + l15 + (tj - 1);
                okA[xq] = ((unsigned)xc < 64u);
                xsA[xq] = okA[xq] ? xc : 0;
                lofs[xq] = (slog ^ (xsA[xq] & 7)) * 8;
            }
            bf16x8 bv[4][4];   // [row][xq], rows ry0..ry0+3
            #pragma unroll
            for (int row = 0; row < 4; ++row)
                #pragma unroll
                for (int xq = 0; xq < 4; ++xq) {
                    bf16x8 v = *(const bf16x8*)&win[((ry0 + row) * 64 + xsA[xq]) * 64
                                                    + lofs[xq]];
                    bf16x8 zz = {};
                    bv[row][xq] = okA[xq] ? v : zz;   // column halo is zero
                }

            __builtin_amdgcn_s_setprio(1);
            #pragma unroll
            for (int ti = 0; ti < 3; ++ti)
                #pragma unroll
                for (int mb = 0; mb < 4; ++mb)
                    #pragma unroll
                    for (int rr = 0; rr < 2; ++rr)
                        #pragma unroll
                        for (int xq = 0; xq < 4; ++xq)
                            acc[mb][rr * 4 + xq] = __builtin_amdgcn_mfma_f32_16x16x32_bf16(
                                A[sp & 1][ti * 4 + mb], bv[rr + ti][xq],
                                acc[mb][rr * 4 + xq], 0, 0, 0);
            __builtin_amdgcn_s_setprio(0);

            // prefetch super-phase sp+2 into the parity just consumed
            if (sp < 4) {
                const int tj2 = (sp + 2) >> 1, s2 = (sp + 2) & 1;
                #pragma unroll
                for (int ti = 0; ti < 3; ++ti)
                    #pragma unroll
                    for (int mb = 0; mb < 4; ++mb)
                        A[sp & 1][ti * 4 + mb] = *(const bf16x8*)(pA
                            + ((ti * 3 + tj2) * 8 + cc * 2 + s2) * 8192 + mb * 512);
            } else if (cc < 3) {   // cross-cc: next cc's super-phase sp-4
                const int tj2 = (sp - 4) >> 1, s2 = (sp - 4) & 1;
                #pragma unroll
                for (int ti = 0; ti < 3; ++ti)
                    #pragma unroll
                    for (int mb = 0; mb < 4; ++mb)
                        A[sp & 1][ti * 4 + mb] = *(const bf16x8*)(pA
                            + ((ti * 3 + tj2) * 8 + (cc + 1) * 2 + s2) * 8192 + mb * 512);
            }
        }
        if (cc < 3) __syncthreads();   // all win reads done before restage
    }

    #pragma unroll
    for (int mb = 0; mb < 4; ++mb) {
        #pragma unroll
        for (int nb = 0; nb < 8; ++nb) {
            int rr = nb >> 2, xq4 = nb & 3;
            int xx = xq4 * 16 + l15;
            int yy = y0 + ry0 + rr;
            #pragma unroll
            for (int rg = 0; rg < 4; ++rg) {
                int o = o_base + m_base + mb * 16 + quad * 4 + rg;
                out[(((size_t)b * OC_ + o) * H_ + yy) * W_ + xx] = acc[mb][nb][rg];
            }
        }
    }
}

// ---------- launcher ----------
extern "C" void kernel_launch(void* const* d_in, const int* in_sizes, int n_in,
                              void* d_out, int out_size, void* d_ws, size_t ws_size,
                              hipStream_t stream) {
    const float* x       = (const float*)d_in[0];
    const float* E       = (const float*)d_in[1];
    const float* rconv_w = (const float*)d_in[2];
    const float* rconv_b = (const float*)d_in[3];
    const float* fc_w    = (const float*)d_in[4];
    const float* fc_b    = (const float*)d_in[5];
    float* out = (float*)d_out;

    char* ws = (char*)d_ws;
    short* xt     = (short*)(ws);                    // 32 MiB
    short* wcomb  = (short*)(ws + 33554432);         // 18 MiB (fragment-ordered)
    float* pooled = (float*)(ws + 52428800);         // 256 KiB
    short* zbuf   = (short*)(ws + 52690944);         // 1 KiB zeros (adjacent to pooled)
    float* rbuf   = (float*)(ws + 52692992);         // 48 KiB

    hipMemsetAsync(pooled, 0, 262144 + 1024, stream);   // pooled + zbuf in one node

    k_transpose_pool<<<dim3(64, 16), 256, 0, stream>>>(x, xt, pooled);
    k_route<<<dim3(64), 256, 0, stream>>>(pooled, rconv_w, rconv_b, fc_w, fc_b, rbuf);
    k_combine<<<dim3(256, 4), 256, 0, stream>>>(E, rbuf, wcomb);
    k_conv<<<dim3(512), 256, 0, stream>>>(xt, wcomb, out, zbuf);
}

// Round 7
// 262.520 us; speedup vs baseline: 1.5079x; 1.5079x over previous
//
#include <hip/hip_runtime.h>

// ---------- constants ----------
#define B_   16
#define C_   256
#define OC_  256
#define H_   64
#define W_   64

typedef __attribute__((ext_vector_type(8))) __bf16 bf16x8;
typedef __attribute__((ext_vector_type(4))) float  f32x4;

__device__ __forceinline__ short f2bf(float f) {
    unsigned u = __float_as_uint(f);
    u += 0x7fffu + ((u >> 16) & 1u);
    return (short)(u >> 16);
}
__device__ __forceinline__ unsigned pk2(float a, float b) {
    return (unsigned(f2bf(a)) & 0xffffu) | (unsigned(f2bf(b)) << 16);
}
__device__ __forceinline__ void gll16(const void* g, void* l) {
    __builtin_amdgcn_global_load_lds(
        (const __attribute__((address_space(1))) unsigned int*)g,
        (__attribute__((address_space(3))) unsigned int*)l,
        16, 0, 0);
}

// ---------- kernel 1: x (fp32, NCHW) -> x_t (bf16, [b][y][x][c]) + pooled atomics ----------
__global__ __launch_bounds__(256) void k_transpose_pool(
        const float* __restrict__ x, short* __restrict__ xt, float* __restrict__ pooled) {
    int y = blockIdx.x, b = blockIdx.y, t = threadIdx.x;
    int si = y >> 4;
    int lane = t & 63, wv = t >> 6;
    int xq = lane & 15, cw = lane >> 4;
    __shared__ float tile[64 * 67];   // stride 67: both phases ~2-way (free)

    for (int cc = 0; cc < 4; ++cc) {
        int cbase = cc * 64;
        if (cc) __syncthreads();
        #pragma unroll
        for (int r = 0; r < 4; ++r) {
            int c_l = r * 16 + wv * 4 + cw;
            float4 v = *(const float4*)&x[(((size_t)b * C_ + cbase + c_l) * H_ + y) * W_ + xq * 4];
            float* tp = &tile[c_l * 67 + xq * 4];
            tp[0] = v.x; tp[1] = v.y; tp[2] = v.z; tp[3] = v.w;
            float s = v.x + v.y + v.z + v.w;       // pooling partial (4 x)
            s += __shfl_xor(s, 1);
            s += __shfl_xor(s, 2);
            if ((lane & 3) == 0)
                atomicAdd(&pooled[((b * 4 + si) * 4 + (xq >> 2)) * 256 + cbase + c_l], s);
        }
        __syncthreads();
        #pragma unroll
        for (int r2 = 0; r2 < 2; ++r2) {
            int u = r2 * 256 + t;
            int xx = u >> 3, cgl = u & 7;
            float f[8];
            #pragma unroll
            for (int j = 0; j < 8; ++j) f[j] = tile[(cgl * 8 + j) * 67 + xx];
            uint4 pkv;
            pkv.x = pk2(f[0], f[1]); pkv.y = pk2(f[2], f[3]);
            pkv.z = pk2(f[4], f[5]); pkv.w = pk2(f[6], f[7]);
            *(uint4*)&xt[(((size_t)b * H_ + y) * W_ + xx) * C_ + cbase + cgl * 8] = pkv;
        }
    }
}

// ---------- kernel 2: routing head -> r[b][k][c] ----------
__global__ __launch_bounds__(256) void k_route(
        const float* __restrict__ pooled, const float* __restrict__ rconv_w,
        const float* __restrict__ rconv_b, const float* __restrict__ fc_w,
        const float* __restrict__ fc_b, float* __restrict__ r_buf) {
    int b = blockIdx.x >> 2;
    int slice = blockIdx.x & 3;
    int t = threadIdx.x;
    int lane = t & 63, wv = t >> 6;
    __shared__ float pl[16][257];
    __shared__ float y1[256];

    #pragma unroll
    for (int q = 0; q < 16; ++q)
        pl[q][t] = pooled[b * 4096 + q * 256 + t] * (1.0f / 256.0f);
    __syncthreads();
    {   // rconv + relu: redundant across the 4 slices (trivial cost)
        int rcc = t >> 4, ss = t & 15;
        float acc = rconv_b[rcc];
        #pragma unroll 8
        for (int c = 0; c < 256; ++c)
            acc += pl[ss][c] * rconv_w[rcc * 256 + c];
        y1[rcc * 16 + ss] = fmaxf(acc, 0.f);
    }
    __syncthreads();
    // fc: 192 outputs per block, 48 per wave
    #pragma unroll 4
    for (int i = 0; i < 48; ++i) {
        int e = slice * 192 + wv * 48 + i;
        const float* row = fc_w + (size_t)e * 256;
        float p = y1[lane]       * row[lane]
                + y1[lane + 64]  * row[lane + 64]
                + y1[lane + 128] * row[lane + 128]
                + y1[lane + 192] * row[lane + 192];
        #pragma unroll
        for (int d = 1; d < 64; d <<= 1)
            p += __shfl_xor(p, d);
        if (lane == 0) {
            float a = fmaxf(p + fc_b[e], 0.f);
            r_buf[(size_t)b * 768 + e] = 1.f / (1.f + __expf(-a));
        }
    }
}

// ---------- kernel 3: combine experts -> wcomb (fragment order), E read ONCE ----------
// Layout: [b][tap9][ccs8][og16] x 1KB-fragment [ol16][quad4][ch8] (shorts).
// Grid 256 (one block per o); block loops all 16 b -> E read 1x (was 4x),
// e-taps hoisted to 27 registers. Per-wave writes: 2 x 64B segments.
__global__ __launch_bounds__(256) void k_combine(
        const float* __restrict__ E, const float* __restrict__ r_buf,
        short* __restrict__ wcomb) {
    int o = blockIdx.x;        // 0..255
    int t = threadIdx.x;
    __shared__ float eT[3][2304];
    #pragma unroll
    for (int k = 0; k < 3; ++k)
        #pragma unroll
        for (int q = 0; q < 9; ++q)
            eT[k][q * 256 + t] = E[((size_t)k * OC_ + o) * 2304 + q * 256 + t];
    __syncthreads();
    int c = t;
    float e0[9], e1[9], e2[9];
    #pragma unroll
    for (int tap = 0; tap < 9; ++tap) {
        e0[tap] = eT[0][c * 9 + tap];
        e1[tap] = eT[1][c * 9 + tap];
        e2[tap] = eT[2][c * 9 + tap];
    }
    int ccs = c >> 5;                                          // cc*2+s (0..7)
    int sub = (o & 15) * 32 + ((c >> 3) & 3) * 8 + (c & 7);    // ol/quad/ch
    int og  = o >> 4;
    for (int b = 0; b < 16; ++b) {
        float r0 = r_buf[(size_t)b * 768 + c];
        float r1 = r_buf[(size_t)b * 768 + 256 + c];
        float r2 = r_buf[(size_t)b * 768 + 512 + c];
        short* wo = wcomb + (size_t)b * 589824;
        #pragma unroll
        for (int tap = 0; tap < 9; ++tap) {
            float v = r0 * e0[tap] + r1 * e1[tap] + r2 * e2[tap];
            wo[((tap * 8 + ccs) * 16 + og) * 512 + sub] = f2bf(v);
        }
    }
}

// ---------- kernel 4: implicit-GEMM conv, R5 structure + LDS halo columns ----------
// R6 post-mortem: register budget is SATURATED (acc 128 AGPR + 128 VGPR =
// 256 = the 2-waves/SIMD ceiling); A[2][12] spilled -> 874MB scratch traffic.
// R7 = R5's proven barrier-free flow (72.4us) made register-neutral faster:
// win [6][66][64] with zeroed halo columns xi=0/65 -> no per-phase clamp or
// cndmask (the halo path was ~6 VALU x 16 reads x 6 phases x 4 cc). gll16
// dest stays wave-linear (8 positions/wave, never crosses a row). Bank
// pattern unchanged (2-way on ds_read_b128 = free).
__global__ __launch_bounds__(256, 2) void k_conv(
        const short* __restrict__ xt, const short* __restrict__ wcomb,
        float* __restrict__ out, const short* __restrict__ zbuf) {
    int lin  = blockIdx.x;
    int work = (lin & 7) * 64 + (lin >> 3);   // XCD-contiguous: 2 samples/XCD
    int b      = work >> 5;
    int o_base = ((work >> 4) & 1) * 128;
    int y0     = (work & 15) * 4;             // 4 output rows per block

    int t = threadIdx.x;
    int lane = t & 63, w = t >> 6;
    int quad = lane >> 4, l15 = lane & 15;

    __shared__ __align__(16) short win[6 * 66 * 64];   // [row][xi0..65][slot8][ch8] 50.7 KB

    int zoff = (int)(zbuf - xt);               // halo rows redirect into zbuf

    // zero halo columns xi=0 / xi=65 once (staging never writes them)
    if (t < 96) {
        int rc = t >> 3, sp = t & 7;
        int row = rc >> 1, col = (rc & 1) ? 65 : 0;
        uint4 z; z.x = z.y = z.z = z.w = 0u;
        *(uint4*)&win[((row * 66 + col) * 8 + sp) * 8] = z;
    }

    // window staging offsets (12 rounds x 256 threads = 3072 tasks)
    int woff[12];
    #pragma unroll
    for (int r = 0; r < 12; ++r) {
        int u = r * 256 + t;
        int pos = u >> 3, sp = u & 7;
        int wrow = pos >> 6, xc = pos & 63;
        int yy = y0 - 1 + wrow;
        int ss = sp ^ ((xc + 1) & 7);           // swizzle keyed to stored xi
        woff[r] = ((unsigned)yy < 64u)
            ? ((b * 64 + yy) * 64 + xc) * 256 + ss * 8
            : zoff;
    }

    int m_base = (w & 1) * 64;
    int ry0    = (w >> 1) * 2;                 // output rows {0,1} or {2,3}

    // A fragment base (shorts): [b][tap][ccs][og][ol][quad][ch]
    const short* pA = wcomb + (size_t)b * 589824
                    + ((o_base + m_base) >> 4) * 512 + l15 * 32 + quad * 8;

    f32x4 acc[4][8];
    #pragma unroll
    for (int i = 0; i < 4; ++i)
        #pragma unroll
        for (int j = 0; j < 8; ++j) acc[i][j] = {0.f, 0.f, 0.f, 0.f};

    for (int cc = 0; cc < 4; ++cc) {
        int ccOff = cc * 64;                   // xt channel offset (shorts)
        int ccA   = cc * 16384;                // A offset (shorts)
        // stage window; dest slot = u + wrow*16 + 8 (66-wide layout, wave-linear)
        #pragma unroll
        for (int r = 0; r < 12; ++r)
            gll16(xt + woff[r] + ccOff,
                  &win[(r * 256 + w * 64 + (((r * 4 + w) >> 3) << 4) + 8) * 8]);

        // preload A phases 0,1 (latency hides under the staging drain)
        bf16x8 P[2][4];
        #pragma unroll
        for (int mb = 0; mb < 4; ++mb) {
            P[0][mb] = *(const bf16x8*)(pA + ccA + mb * 512);
            P[1][mb] = *(const bf16x8*)(pA + ccA + 8192 + mb * 512);
        }
        __syncthreads();   // win ready (drains gll16 + halo init on cc==0)

        // 18 phases = 9 taps x 2 k-slots; NO barriers inside.
        #pragma unroll
        for (int ph = 0; ph < 18; ++ph) {
            const int tp = ph >> 1, s = ph & 1;
            const int ti = tp / 3, tj = tp % 3;
            const int cur = ph & 1;
            int slog = s * 4 + quad;

            bf16x8 bv[8];
            #pragma unroll
            for (int nb = 0; nb < 8; ++nb) {
                int rr = nb >> 2, xq4 = nb & 3;
                int xi = xq4 * 16 + l15 + tj;        // 0..65, halo cols are zeros
                int wrow = ry0 + rr + ti;            // 0..5
                bv[nb] = *(const bf16x8*)&win[((wrow * 66 + xi) * 8
                                               + (slog ^ (xi & 7))) * 8];
            }
            __builtin_amdgcn_s_setprio(1);
            #pragma unroll
            for (int mb = 0; mb < 4; ++mb)
                #pragma unroll
                for (int nb = 0; nb < 8; ++nb)
                    acc[mb][nb] = __builtin_amdgcn_mfma_f32_16x16x32_bf16(
                        P[cur][mb], bv[nb], acc[mb][nb], 0, 0, 0);
            __builtin_amdgcn_s_setprio(0);

            // prefetch phase ph+2 into the parity just consumed (coalesced 1KB x4)
            if (ph < 16) {
                const int np = ph + 2, ntp = np >> 1, ns = np & 1;
                #pragma unroll
                for (int mb = 0; mb < 4; ++mb)
                    P[cur][mb] = *(const bf16x8*)(pA + ccA + ntp * 65536
                                                  + ns * 8192 + mb * 512);
            }
        }
        if (cc < 3) __syncthreads();   // all win reads done before restage
    }

    #pragma unroll
    for (int mb = 0; mb < 4; ++mb) {
        #pragma unroll
        for (int nb = 0; nb < 8; ++nb) {
            int rr = nb >> 2, xq4 = nb & 3;
            int xx = xq4 * 16 + l15;
            int yy = y0 + ry0 + rr;
            #pragma unroll
            for (int rg = 0; rg < 4; ++rg) {
                int o = o_base + m_base + mb * 16 + quad * 4 + rg;
                out[(((size_t)b * OC_ + o) * H_ + yy) * W_ + xx] = acc[mb][nb][rg];
            }
        }
    }
}

// ---------- launcher ----------
extern "C" void kernel_launch(void* const* d_in, const int* in_sizes, int n_in,
                              void* d_out, int out_size, void* d_ws, size_t ws_size,
                              hipStream_t stream) {
    const float* x       = (const float*)d_in[0];
    const float* E       = (const float*)d_in[1];
    const float* rconv_w = (const float*)d_in[2];
    const float* rconv_b = (const float*)d_in[3];
    const float* fc_w    = (const float*)d_in[4];
    const float* fc_b    = (const float*)d_in[5];
    float* out = (float*)d_out;

    char* ws = (char*)d_ws;
    short* xt     = (short*)(ws);                    // 32 MiB
    short* wcomb  = (short*)(ws + 33554432);         // 18 MiB (fragment-ordered)
    float* pooled = (float*)(ws + 52428800);         // 256 KiB
    short* zbuf   = (short*)(ws + 52690944);         // 1 KiB zeros (adjacent to pooled)
    float* rbuf   = (float*)(ws + 52692992);         // 48 KiB

    hipMemsetAsync(pooled, 0, 262144 + 1024, stream);   // pooled + zbuf in one node

    k_transpose_pool<<<dim3(64, 16), 256, 0, stream>>>(x, xt, pooled);
    k_route<<<dim3(64), 256, 0, stream>>>(pooled, rconv_w, rconv_b, fc_w, fc_b, rbuf);
    k_combine<<<dim3(256), 256, 0, stream>>>(E, rbuf, wcomb);
    k_conv<<<dim3(512), 256, 0, stream>>>(xt, wcomb, out, zbuf);
}

// Round 8
// 241.670 us; speedup vs baseline: 1.6380x; 1.0863x over previous
//
#include <hip/hip_runtime.h>

// ---------- constants ----------
#define B_   16
#define C_   256
#define OC_  256
#define H_   64
#define W_   64

typedef __attribute__((ext_vector_type(8))) __bf16 bf16x8;
typedef __attribute__((ext_vector_type(4))) float  f32x4;

__device__ __forceinline__ short f2bf(float f) {
    unsigned u = __float_as_uint(f);
    u += 0x7fffu + ((u >> 16) & 1u);
    return (short)(u >> 16);
}
__device__ __forceinline__ unsigned pk2(float a, float b) {
    return (unsigned(f2bf(a)) & 0xffffu) | (unsigned(f2bf(b)) << 16);
}
__device__ __forceinline__ void gll16(const void* g, void* l) {
    __builtin_amdgcn_global_load_lds(
        (const __attribute__((address_space(1))) unsigned int*)g,
        (__attribute__((address_space(3))) unsigned int*)l,
        16, 0, 0);
}

// ---------- kernel 1: x (fp32, NCHW) -> x_t (bf16, [b][y][x][c]) + pooled atomics ----------
__global__ __launch_bounds__(256) void k_transpose_pool(
        const float* __restrict__ x, short* __restrict__ xt, float* __restrict__ pooled) {
    int y = blockIdx.x, b = blockIdx.y, t = threadIdx.x;
    int si = y >> 4;
    int lane = t & 63, wv = t >> 6;
    int xq = lane & 15, cw = lane >> 4;
    __shared__ float tile[64 * 67];   // stride 67: both phases ~2-way (free)

    for (int cc = 0; cc < 4; ++cc) {
        int cbase = cc * 64;
        if (cc) __syncthreads();
        #pragma unroll
        for (int r = 0; r < 4; ++r) {
            int c_l = r * 16 + wv * 4 + cw;
            float4 v = *(const float4*)&x[(((size_t)b * C_ + cbase + c_l) * H_ + y) * W_ + xq * 4];
            float* tp = &tile[c_l * 67 + xq * 4];
            tp[0] = v.x; tp[1] = v.y; tp[2] = v.z; tp[3] = v.w;
            float s = v.x + v.y + v.z + v.w;       // pooling partial (4 x)
            s += __shfl_xor(s, 1);
            s += __shfl_xor(s, 2);
            if ((lane & 3) == 0)
                atomicAdd(&pooled[((b * 4 + si) * 4 + (xq >> 2)) * 256 + cbase + c_l], s);
        }
        __syncthreads();
        #pragma unroll
        for (int r2 = 0; r2 < 2; ++r2) {
            int u = r2 * 256 + t;
            int xx = u >> 3, cgl = u & 7;
            float f[8];
            #pragma unroll
            for (int j = 0; j < 8; ++j) f[j] = tile[(cgl * 8 + j) * 67 + xx];
            uint4 pkv;
            pkv.x = pk2(f[0], f[1]); pkv.y = pk2(f[2], f[3]);
            pkv.z = pk2(f[4], f[5]); pkv.w = pk2(f[6], f[7]);
            *(uint4*)&xt[(((size_t)b * H_ + y) * W_ + xx) * C_ + cbase + cgl * 8] = pkv;
        }
    }
}

// ---------- kernel 2: routing head -> r[b][k][c] (R0 original; R4 rewrite cost +8us) ----------
__global__ __launch_bounds__(256) void k_route(
        const float* __restrict__ pooled, const float* __restrict__ rconv_w,
        const float* __restrict__ rconv_b, const float* __restrict__ fc_w,
        const float* __restrict__ fc_b, float* __restrict__ r_buf) {
    int b = blockIdx.x;
    int t = threadIdx.x;
    __shared__ float pl[16][257];
    __shared__ float y1[256];

    #pragma unroll
    for (int q = 0; q < 16; ++q)
        pl[q][t] = pooled[b * 4096 + q * 256 + t] * (1.0f / 256.0f);
    __syncthreads();
    {
        int rcc = t >> 4, ss = t & 15;
        float acc = rconv_b[rcc];
        #pragma unroll 8
        for (int c = 0; c < 256; ++c)
            acc += pl[ss][c] * rconv_w[rcc * 256 + c];
        y1[rcc * 16 + ss] = fmaxf(acc, 0.f);
    }
    __syncthreads();
    for (int e0 = 0; e0 < 768; e0 += 256) {
        int e = e0 + t;
        float acc = fc_b[e];
        #pragma unroll 8
        for (int q = 0; q < 256; ++q)
            acc += y1[q] * fc_w[(size_t)e * 256 + q];
        acc = fmaxf(acc, 0.f);
        r_buf[(size_t)b * 768 + e] = 1.f / (1.f + __expf(-acc));
    }
}

// ---------- kernel 3: combine experts -> wcomb (fragment order), E read ONCE ----------
// Layout: [b][tap9][ccs8][og16] x 1KB-fragment [ol16][quad4][ch8] (shorts).
// Grid 256 (one block per o); block loops all 16 b -> E read 1x,
// e-taps hoisted to 27 registers. Per-wave writes: 64B segments.
__global__ __launch_bounds__(256) void k_combine(
        const float* __restrict__ E, const float* __restrict__ r_buf,
        short* __restrict__ wcomb) {
    int o = blockIdx.x;        // 0..255
    int t = threadIdx.x;
    __shared__ float eT[3][2304];
    #pragma unroll
    for (int k = 0; k < 3; ++k)
        #pragma unroll
        for (int q = 0; q < 9; ++q)
            eT[k][q * 256 + t] = E[((size_t)k * OC_ + o) * 2304 + q * 256 + t];
    __syncthreads();
    int c = t;
    float e0[9], e1[9], e2[9];
    #pragma unroll
    for (int tap = 0; tap < 9; ++tap) {
        e0[tap] = eT[0][c * 9 + tap];
        e1[tap] = eT[1][c * 9 + tap];
        e2[tap] = eT[2][c * 9 + tap];
    }
    int ccs = c >> 5;                                          // cc*2+s (0..7)
    int sub = (o & 15) * 32 + ((c >> 3) & 3) * 8 + (c & 7);    // ol/quad/ch
    int og  = o >> 4;
    for (int b = 0; b < 16; ++b) {
        float r0 = r_buf[(size_t)b * 768 + c];
        float r1 = r_buf[(size_t)b * 768 + 256 + c];
        float r2 = r_buf[(size_t)b * 768 + 512 + c];
        short* wo = wcomb + (size_t)b * 589824;
        #pragma unroll
        for (int tap = 0; tap < 9; ++tap) {
            float v = r0 * e0[tap] + r1 * e1[tap] + r2 * e2[tap];
            wo[((tap * 8 + ccs) * 16 + og) * 512 + sub] = f2bf(v);
        }
    }
}

// ---------- kernel 4: implicit-GEMM conv (R5 structure restored verbatim) ----------
// R7 post-mortem: the 66-wide halo rewrite caused a small register spill
// (FETCH 32->100MB, WRITE 74->104MB at capped VGPR=128) -> reverted.
// R5's proven flow: barrier-free 18 phases, A from fragment-ordered wcomb
// via coalesced 1KB loads into P[2][4] reg ping-pong, win 48KB clamp-halo.
// Only change vs R5: pA lane offset matches the [ol][quad][ch] fragment
// (register-neutral; wave still reads one contiguous 1KB span).
__global__ __launch_bounds__(256, 2) void k_conv(
        const short* __restrict__ xt, const short* __restrict__ wcomb,
        float* __restrict__ out, const short* __restrict__ zbuf) {
    int lin  = blockIdx.x;
    int work = (lin & 7) * 64 + (lin >> 3);   // XCD-contiguous: 2 samples/XCD
    int b      = work >> 5;
    int o_base = ((work >> 4) & 1) * 128;
    int y0     = (work & 15) * 4;             // 4 output rows per block

    int t = threadIdx.x;
    int lane = t & 63, w = t >> 6;
    int quad = lane >> 4, l15 = lane & 15;

    __shared__ __align__(16) short win[6 * 64 * 64];   // rows y0-1..y0+4, 48 KB only

    int zoff = (int)(zbuf - xt);               // halo rows redirect into zbuf

    // window staging offsets (12 rounds x 256 threads = 3072 tasks)
    int woff[12];
    #pragma unroll
    for (int r = 0; r < 12; ++r) {
        int u = r * 256 + t;
        int pos = u >> 3, sp = u & 7;
        int wrow = pos >> 6, xc = pos & 63;
        int yy = y0 - 1 + wrow;
        int ss = sp ^ (xc & 7);                 // XOR swizzle at source
        woff[r] = ((unsigned)yy < 64u)
            ? ((b * 64 + yy) * 64 + xc) * 256 + ss * 8
            : zoff;
    }

    int m_base = (w & 1) * 64;
    int ry0    = (w >> 1) * 2;                 // output rows {0,1} or {2,3}

    // A fragment base (shorts): [b][tap][ccs][og] x [ol][quad][ch]
    const short* pA = wcomb + (size_t)b * 589824
                    + ((o_base + m_base) >> 4) * 512 + l15 * 32 + quad * 8;

    f32x4 acc[4][8];
    #pragma unroll
    for (int i = 0; i < 4; ++i)
        #pragma unroll
        for (int j = 0; j < 8; ++j) acc[i][j] = {0.f, 0.f, 0.f, 0.f};

    for (int cc = 0; cc < 4; ++cc) {
        int ccOff = cc * 64;                   // xt channel offset (shorts)
        int ccA   = cc * 16384;                // A offset (shorts)
        // stage window (direct-to-LDS; prev-cc tail barrier protects reuse)
        #pragma unroll
        for (int r = 0; r < 12; ++r)
            gll16(xt + woff[r] + ccOff, &win[(r * 256 + w * 64) * 8]);

        // preload A phases 0,1 (latency hides under the staging drain)
        bf16x8 P[2][4];
        #pragma unroll
        for (int mb = 0; mb < 4; ++mb) {
            P[0][mb] = *(const bf16x8*)(pA + ccA + mb * 512);
            P[1][mb] = *(const bf16x8*)(pA + ccA + 8192 + mb * 512);
        }
        __syncthreads();   // win ready (drains gll16 + A preloads)

        // 18 phases = 9 taps x 2 k-slots; NO barriers inside.
        #pragma unroll
        for (int ph = 0; ph < 18; ++ph) {
            const int tp = ph >> 1, s = ph & 1;
            const int ti = tp / 3, tj = tp % 3;
            const int cur = ph & 1;
            int slog = s * 4 + quad;

            bf16x8 bv[8];
            #pragma unroll
            for (int nb = 0; nb < 8; ++nb) {
                int rr = nb >> 2, xq4 = nb & 3;
                int xc = xq4 * 16 + l15 + (tj - 1);
                bool ok = ((unsigned)xc < 64u);
                int xs = ok ? xc : 0;
                int wrow = ry0 + rr + ti;    // 0..5
                bf16x8 v = *(const bf16x8*)&win[(wrow * 64 + xs) * 64
                                                + ((slog ^ (xs & 7)) * 8)];
                bf16x8 zz = {};
                bv[nb] = ok ? v : zz;        // column halo is zero
            }
            __builtin_amdgcn_s_setprio(1);
            #pragma unroll
            for (int mb = 0; mb < 4; ++mb)
                #pragma unroll
                for (int nb = 0; nb < 8; ++nb)
                    acc[mb][nb] = __builtin_amdgcn_mfma_f32_16x16x32_bf16(
                        P[cur][mb], bv[nb], acc[mb][nb], 0, 0, 0);
            __builtin_amdgcn_s_setprio(0);

            // prefetch phase ph+2 into the parity just consumed (coalesced 1KB x4)
            if (ph < 16) {
                const int np = ph + 2, ntp = np >> 1, ns = np & 1;
                #pragma unroll
                for (int mb = 0; mb < 4; ++mb)
                    P[cur][mb] = *(const bf16x8*)(pA + ccA + ntp * 65536
                                                  + ns * 8192 + mb * 512);
            }
        }
        if (cc < 3) __syncthreads();   // all win reads done before restage
    }

    #pragma unroll
    for (int mb = 0; mb < 4; ++mb) {
        #pragma unroll
        for (int nb = 0; nb < 8; ++nb) {
            int rr = nb >> 2, xq4 = nb & 3;
            int xx = xq4 * 16 + l15;
            int yy = y0 + ry0 + rr;
            #pragma unroll
            for (int rg = 0; rg < 4; ++rg) {
                int o = o_base + m_base + mb * 16 + quad * 4 + rg;
                out[(((size_t)b * OC_ + o) * H_ + yy) * W_ + xx] = acc[mb][nb][rg];
            }
        }
    }
}

// ---------- launcher ----------
extern "C" void kernel_launch(void* const* d_in, const int* in_sizes, int n_in,
                              void* d_out, int out_size, void* d_ws, size_t ws_size,
                              hipStream_t stream) {
    const float* x       = (const float*)d_in[0];
    const float* E       = (const float*)d_in[1];
    const float* rconv_w = (const float*)d_in[2];
    const float* rconv_b = (const float*)d_in[3];
    const float* fc_w    = (const float*)d_in[4];
    const float* fc_b    = (const float*)d_in[5];
    float* out = (float*)d_out;

    char* ws = (char*)d_ws;
    short* xt     = (short*)(ws);                    // 32 MiB
    short* wcomb  = (short*)(ws + 33554432);         // 18 MiB (fragment-ordered)
    float* pooled = (float*)(ws + 52428800);         // 256 KiB
    short* zbuf   = (short*)(ws + 52690944);         // 1 KiB zeros (adjacent to pooled)
    float* rbuf   = (float*)(ws + 52692992);         // 48 KiB

    hipMemsetAsync(pooled, 0, 262144 + 1024, stream);   // pooled + zbuf in one node

    k_transpose_pool<<<dim3(64, 16), 256, 0, stream>>>(x, xt, pooled);
    k_route<<<dim3(16), 256, 0, stream>>>(pooled, rconv_w, rconv_b, fc_w, fc_b, rbuf);
    k_combine<<<dim3(256), 256, 0, stream>>>(E, rbuf, wcomb);
    k_conv<<<dim3(512), 256, 0, stream>>>(xt, wcomb, out, zbuf);
}